// Round 1
// baseline (87.782 us; speedup 1.0000x reference)
//
#include <hip/hip_runtime.h>

// Binary cross-entropy style loss reduction.
// out = -sum_i[ y*log_sigmoid(x) + (1-y)*log_sigmoid(-x) ] / ((1+neg)*pos)
// log_sigmoid(z) = min(z,0) - log1p(exp(-|z|))  (stable form)
// With y in {0,1}: per-element term = log_sigmoid(label ? x : -x).

__global__ __launch_bounds__(256) void bce_reduce_kernel(
    const float* __restrict__ x,
    const int* __restrict__ lab,
    double* __restrict__ sum_out,          // ws[0]: double loss sum
    unsigned int* __restrict__ pos_out,    // ws[8]: uint positive count
    int n)
{
    const int n4 = n >> 2;
    const float4* __restrict__ x4 = reinterpret_cast<const float4*>(x);
    const int4*   __restrict__ l4 = reinterpret_cast<const int4*>(lab);

    float lsum = 0.0f;
    int pcnt = 0;

    int idx = blockIdx.x * blockDim.x + threadIdx.x;
    int stride = gridDim.x * blockDim.x;

    for (int i = idx; i < n4; i += stride) {
        float4 xv = x4[i];
        int4   lv = l4[i];
        float xs[4] = {xv.x, xv.y, xv.z, xv.w};
        int   ls[4] = {lv.x, lv.y, lv.z, lv.w};
#pragma unroll
        for (int j = 0; j < 4; ++j) {
            int p = (ls[j] != 0) ? 1 : 0;
            pcnt += p;
            float z  = p ? xs[j] : -xs[j];
            float az = fabsf(z);
            // log_sigmoid(z) = min(z,0) - log1p(exp(-|z|))
            float t = __expf(-az);              // in (0,1], no overflow
            lsum += fminf(z, 0.0f) - __logf(1.0f + t);
        }
    }

    // scalar tail (n not multiple of 4) handled by global thread 0
    if (idx == 0) {
        for (int i = n4 << 2; i < n; ++i) {
            int p = (lab[i] != 0) ? 1 : 0;
            pcnt += p;
            float z  = p ? x[i] : -x[i];
            float az = fabsf(z);
            lsum += fminf(z, 0.0f) - __logf(1.0f + __expf(-az));
        }
    }

    // wave (64-lane) reduction
#pragma unroll
    for (int off = 32; off > 0; off >>= 1) {
        lsum += __shfl_down(lsum, off);
        pcnt += __shfl_down(pcnt, off);
    }

    // cross-wave reduction via LDS (256 threads = 4 waves)
    __shared__ float wsum[4];
    __shared__ int   wcnt[4];
    int wave = threadIdx.x >> 6;
    int lane = threadIdx.x & 63;
    if (lane == 0) { wsum[wave] = lsum; wcnt[wave] = pcnt; }
    __syncthreads();
    if (threadIdx.x == 0) {
        float bs = wsum[0] + wsum[1] + wsum[2] + wsum[3];
        int   bc = wcnt[0] + wcnt[1] + wcnt[2] + wcnt[3];
        atomicAdd(sum_out, (double)bs);
        atomicAdd(pos_out, (unsigned int)bc);
    }
}

__global__ void bce_finalize_kernel(const double* __restrict__ sum_in,
                                    const unsigned int* __restrict__ pos_in,
                                    float* __restrict__ out, int n)
{
    double s   = sum_in[0];
    double pos = (double)pos_in[0];
    double neg = (double)n - pos;
    double scale = -1.0 / ((1.0 + neg) * pos);
    out[0] = (float)(scale * s);
}

extern "C" void kernel_launch(void* const* d_in, const int* in_sizes, int n_in,
                              void* d_out, int out_size, void* d_ws, size_t ws_size,
                              hipStream_t stream) {
    const float* x   = (const float*)d_in[0];
    const int*   lab = (const int*)d_in[1];
    int n = in_sizes[0];
    float* out = (float*)d_out;

    double* dsum       = (double*)d_ws;
    unsigned int* dpos = (unsigned int*)((char*)d_ws + 8);

    // zero the 16-byte accumulator region every call (ws is not re-poisoned
    // between replays; we must not carry state)
    hipMemsetAsync(d_ws, 0, 16, stream);

    int blocks = 2048;   // 256 CU * 8 blocks; grid-stride covers the rest
    bce_reduce_kernel<<<blocks, 256, 0, stream>>>(x, lab, dsum, dpos, n);
    bce_finalize_kernel<<<1, 1, 0, stream>>>(dsum, dpos, out, n);
}

// Round 2
// 77.832 us; speedup vs baseline: 1.1278x; 1.1278x over previous
//
#include <hip/hip_runtime.h>

// out = -sum_i[ y*log_sigmoid(x) + (1-y)*log_sigmoid(-x) ] / ((1+neg)*pos)
// per-element with z = (label ? x : -x):
//   term = min(z,0) - log1p(exp(-|z|)),  and |z| == |x|
//   min(z,0) = label ? min(x,0) : min(-x,0)

__device__ __forceinline__ void bce_elem(float xv, int lv, float& lsum, int& pcnt)
{
    int p = (lv != 0) ? 1 : 0;
    pcnt += p;
    float ax = fabsf(xv);
    float t  = __expf(-ax);            // in (0,1], no overflow
    float c  = __logf(1.0f + t);       // log1p(exp(-|x|)) >= 0
    float zm = p ? fminf(xv, 0.0f) : fminf(-xv, 0.0f);
    lsum += zm - c;
}

__global__ __launch_bounds__(256) void bce_reduce_kernel(
    const float* __restrict__ x,
    const int* __restrict__ lab,
    double* __restrict__ sum_out,          // ws[0]: double loss sum
    unsigned int* __restrict__ pos_out,    // ws[8]: uint positive count
    int n)
{
    const int n4 = n >> 2;
    const float4* __restrict__ x4 = reinterpret_cast<const float4*>(x);
    const int4*   __restrict__ l4 = reinterpret_cast<const int4*>(lab);

    float lsum = 0.0f;
    int pcnt = 0;

    const int tid    = blockIdx.x * blockDim.x + threadIdx.x;
    const int stride = gridDim.x * blockDim.x;

    int i = tid;
    // 4x unrolled: 8 independent loads in flight before any dependent use
    for (; i + 3 * stride < n4; i += 4 * stride) {
        float4 a0 = x4[i];
        float4 a1 = x4[i + stride];
        float4 a2 = x4[i + 2 * stride];
        float4 a3 = x4[i + 3 * stride];
        int4   b0 = l4[i];
        int4   b1 = l4[i + stride];
        int4   b2 = l4[i + 2 * stride];
        int4   b3 = l4[i + 3 * stride];

        bce_elem(a0.x, b0.x, lsum, pcnt); bce_elem(a0.y, b0.y, lsum, pcnt);
        bce_elem(a0.z, b0.z, lsum, pcnt); bce_elem(a0.w, b0.w, lsum, pcnt);
        bce_elem(a1.x, b1.x, lsum, pcnt); bce_elem(a1.y, b1.y, lsum, pcnt);
        bce_elem(a1.z, b1.z, lsum, pcnt); bce_elem(a1.w, b1.w, lsum, pcnt);
        bce_elem(a2.x, b2.x, lsum, pcnt); bce_elem(a2.y, b2.y, lsum, pcnt);
        bce_elem(a2.z, b2.z, lsum, pcnt); bce_elem(a2.w, b2.w, lsum, pcnt);
        bce_elem(a3.x, b3.x, lsum, pcnt); bce_elem(a3.y, b3.y, lsum, pcnt);
        bce_elem(a3.z, b3.z, lsum, pcnt); bce_elem(a3.w, b3.w, lsum, pcnt);
    }
    // remaining float4 groups
    for (; i < n4; i += stride) {
        float4 a = x4[i];
        int4   b = l4[i];
        bce_elem(a.x, b.x, lsum, pcnt); bce_elem(a.y, b.y, lsum, pcnt);
        bce_elem(a.z, b.z, lsum, pcnt); bce_elem(a.w, b.w, lsum, pcnt);
    }
    // scalar tail (n not multiple of 4) handled by global thread 0
    if (tid == 0) {
        for (int k = n4 << 2; k < n; ++k)
            bce_elem(x[k], lab[k], lsum, pcnt);
    }

    // wave (64-lane) reduction
#pragma unroll
    for (int off = 32; off > 0; off >>= 1) {
        lsum += __shfl_down(lsum, off);
        pcnt += __shfl_down(pcnt, off);
    }

    // cross-wave reduction via LDS (256 threads = 4 waves)
    __shared__ float wsum[4];
    __shared__ int   wcnt[4];
    int wave = threadIdx.x >> 6;
    int lane = threadIdx.x & 63;
    if (lane == 0) { wsum[wave] = lsum; wcnt[wave] = pcnt; }
    __syncthreads();
    if (threadIdx.x == 0) {
        float bs = wsum[0] + wsum[1] + wsum[2] + wsum[3];
        int   bc = wcnt[0] + wcnt[1] + wcnt[2] + wcnt[3];
        atomicAdd(sum_out, (double)bs);
        atomicAdd(pos_out, (unsigned int)bc);
    }
}

__global__ void bce_finalize_kernel(const double* __restrict__ sum_in,
                                    const unsigned int* __restrict__ pos_in,
                                    float* __restrict__ out, int n)
{
    double s   = sum_in[0];
    double pos = (double)pos_in[0];
    double neg = (double)n - pos;
    double scale = -1.0 / ((1.0 + neg) * pos);
    out[0] = (float)(scale * s);
}

extern "C" void kernel_launch(void* const* d_in, const int* in_sizes, int n_in,
                              void* d_out, int out_size, void* d_ws, size_t ws_size,
                              hipStream_t stream) {
    const float* x   = (const float*)d_in[0];
    const int*   lab = (const int*)d_in[1];
    int n = in_sizes[0];
    float* out = (float*)d_out;

    double* dsum       = (double*)d_ws;
    unsigned int* dpos = (unsigned int*)((char*)d_ws + 8);

    // zero the 16-byte accumulator region every call (ws is not re-poisoned
    // between replays; we must not carry state)
    hipMemsetAsync(d_ws, 0, 16, stream);

    int blocks = 2048;   // 256 CU * 8 blocks; grid-stride covers the rest
    bce_reduce_kernel<<<blocks, 256, 0, stream>>>(x, lab, dsum, dpos, n);
    bce_finalize_kernel<<<1, 1, 0, stream>>>(dsum, dpos, out, n);
}

// Round 3
// 50.542 us; speedup vs baseline: 1.7368x; 1.5400x over previous
//
#include <hip/hip_runtime.h>

// out = -sum_i[ y*log_sigmoid(x) + (1-y)*log_sigmoid(-x) ] / ((1+neg)*pos)
// per-element with z = (label ? x : -x):
//   term = min(z,0) - log1p(exp(-|z|)),  and |z| == |x|
//
// Stage 1: 2048 blocks, grid-stride float4/int4, per-block partial (float sum,
//          int pos-count) written to d_ws — NO global atomics.
// Stage 2: one block reduces the 2048 partials in double and finalizes.

#define NBLOCKS 2048
#define TPB 256

__device__ __forceinline__ void bce_elem(float xv, int lv, float& lsum, int& pcnt)
{
    int p = (lv != 0) ? 1 : 0;
    pcnt += p;
    float ax = fabsf(xv);
    float t  = __expf(-ax);            // in (0,1], no overflow
    float c  = __logf(1.0f + t);       // log1p(exp(-|x|)) >= 0
    float z  = p ? xv : -xv;
    lsum += fminf(z, 0.0f) - c;
}

__global__ __launch_bounds__(TPB, 8) void bce_reduce_kernel(
    const float* __restrict__ x,
    const int* __restrict__ lab,
    float* __restrict__ psum,      // [NBLOCKS] per-block loss partials
    int*   __restrict__ pcount,    // [NBLOCKS] per-block positive counts
    int n)
{
    const int n4 = n >> 2;
    const float4* __restrict__ x4 = reinterpret_cast<const float4*>(x);
    const int4*   __restrict__ l4 = reinterpret_cast<const int4*>(lab);

    float lsum = 0.0f;
    int pcnt = 0;

    const int tid    = blockIdx.x * TPB + threadIdx.x;
    const int stride = gridDim.x * TPB;

    int i = tid;
    // 4x unrolled: 8 independent loads in flight before any dependent use
    for (; i + 3 * stride < n4; i += 4 * stride) {
        float4 a0 = x4[i];
        float4 a1 = x4[i + stride];
        float4 a2 = x4[i + 2 * stride];
        float4 a3 = x4[i + 3 * stride];
        int4   b0 = l4[i];
        int4   b1 = l4[i + stride];
        int4   b2 = l4[i + 2 * stride];
        int4   b3 = l4[i + 3 * stride];

        bce_elem(a0.x, b0.x, lsum, pcnt); bce_elem(a0.y, b0.y, lsum, pcnt);
        bce_elem(a0.z, b0.z, lsum, pcnt); bce_elem(a0.w, b0.w, lsum, pcnt);
        bce_elem(a1.x, b1.x, lsum, pcnt); bce_elem(a1.y, b1.y, lsum, pcnt);
        bce_elem(a1.z, b1.z, lsum, pcnt); bce_elem(a1.w, b1.w, lsum, pcnt);
        bce_elem(a2.x, b2.x, lsum, pcnt); bce_elem(a2.y, b2.y, lsum, pcnt);
        bce_elem(a2.z, b2.z, lsum, pcnt); bce_elem(a2.w, b2.w, lsum, pcnt);
        bce_elem(a3.x, b3.x, lsum, pcnt); bce_elem(a3.y, b3.y, lsum, pcnt);
        bce_elem(a3.z, b3.z, lsum, pcnt); bce_elem(a3.w, b3.w, lsum, pcnt);
    }
    for (; i < n4; i += stride) {
        float4 a = x4[i];
        int4   b = l4[i];
        bce_elem(a.x, b.x, lsum, pcnt); bce_elem(a.y, b.y, lsum, pcnt);
        bce_elem(a.z, b.z, lsum, pcnt); bce_elem(a.w, b.w, lsum, pcnt);
    }
    if (tid == 0) {  // scalar tail (n not multiple of 4)
        for (int k = n4 << 2; k < n; ++k)
            bce_elem(x[k], lab[k], lsum, pcnt);
    }

    // wave (64-lane) reduction
#pragma unroll
    for (int off = 32; off > 0; off >>= 1) {
        lsum += __shfl_down(lsum, off);
        pcnt += __shfl_down(pcnt, off);
    }

    // cross-wave reduction via LDS (4 waves)
    __shared__ float wsum[4];
    __shared__ int   wcnt[4];
    int wave = threadIdx.x >> 6;
    int lane = threadIdx.x & 63;
    if (lane == 0) { wsum[wave] = lsum; wcnt[wave] = pcnt; }
    __syncthreads();
    if (threadIdx.x == 0) {
        psum[blockIdx.x]   = wsum[0] + wsum[1] + wsum[2] + wsum[3];
        pcount[blockIdx.x] = wcnt[0] + wcnt[1] + wcnt[2] + wcnt[3];
    }
}

__global__ __launch_bounds__(256) void bce_finalize_kernel(
    const float* __restrict__ psum,
    const int*   __restrict__ pcount,
    float* __restrict__ out, int n, int nparts)
{
    double s = 0.0;
    int    c = 0;
    for (int i = threadIdx.x; i < nparts; i += 256) {
        s += (double)psum[i];
        c += pcount[i];
    }
#pragma unroll
    for (int off = 32; off > 0; off >>= 1) {
        s += __shfl_down(s, off);
        c += __shfl_down(c, off);
    }
    __shared__ double wsd[4];
    __shared__ int    wci[4];
    int wave = threadIdx.x >> 6;
    int lane = threadIdx.x & 63;
    if (lane == 0) { wsd[wave] = s; wci[wave] = c; }
    __syncthreads();
    if (threadIdx.x == 0) {
        double stot = wsd[0] + wsd[1] + wsd[2] + wsd[3];
        double pos  = (double)(wci[0] + wci[1] + wci[2] + wci[3]);
        double neg  = (double)n - pos;
        double scale = -1.0 / ((1.0 + neg) * pos);
        out[0] = (float)(scale * stot);
    }
}

extern "C" void kernel_launch(void* const* d_in, const int* in_sizes, int n_in,
                              void* d_out, int out_size, void* d_ws, size_t ws_size,
                              hipStream_t stream) {
    const float* x   = (const float*)d_in[0];
    const int*   lab = (const int*)d_in[1];
    int n = in_sizes[0];
    float* out = (float*)d_out;

    // ws layout: [0, 8KB) float partial sums, [8KB, 16KB) int partial counts.
    // Every slot is written unconditionally each call -> no memset needed,
    // no state carried across replays.
    float* psum  = (float*)d_ws;
    int*   pcnt  = (int*)((char*)d_ws + NBLOCKS * sizeof(float));

    bce_reduce_kernel<<<NBLOCKS, TPB, 0, stream>>>(x, lab, psum, pcnt, n);
    bce_finalize_kernel<<<1, 256, 0, stream>>>(psum, pcnt, out, n, NBLOCKS);
}